// Round 1
// baseline (411.214 us; speedup 1.0000x reference)
//
#include <hip/hip_runtime.h>
#include <hip/hip_fp16.h>

#define D_FEAT 128
#define SCAN_B 1024

typedef float f32x2 __attribute__((ext_vector_type(2)));

// --- 1. both degree histograms in one pass: counters are 0.8 MB -> L2-resident atomics ---
__global__ void degree_kernel(const int* __restrict__ src, const int* __restrict__ dst,
                              int* __restrict__ deg_o, int* __restrict__ deg_i, int n_edges) {
    int t = blockIdx.x * blockDim.x + threadIdx.x;
    int e = t * 4;
    if (e + 3 < n_edges) {
        int4 s4 = *(const int4*)(src + e);
        int4 d4 = *(const int4*)(dst + e);
        atomicAdd(&deg_o[s4.x], 1); atomicAdd(&deg_o[s4.y], 1);
        atomicAdd(&deg_o[s4.z], 1); atomicAdd(&deg_o[s4.w], 1);
        atomicAdd(&deg_i[d4.x], 1); atomicAdd(&deg_i[d4.y], 1);
        atomicAdd(&deg_i[d4.z], 1); atomicAdd(&deg_i[d4.w], 1);
    } else {
        for (int i = e; i < n_edges; i++) {
            atomicAdd(&deg_o[src[i]], 1);
            atomicAdd(&deg_i[dst[i]], 1);
        }
    }
}

// --- 2a. per-block exclusive scan of in-degree (local), block totals to bsum ---
__global__ __launch_bounds__(SCAN_B) void scan1_kernel(const int* __restrict__ deg_i,
        int* __restrict__ off, int* __restrict__ bsum, int n) {
    __shared__ int sh[SCAN_B];
    int t = threadIdx.x;
    int g = blockIdx.x * SCAN_B + t;
    int v = (g < n) ? deg_i[g] : 0;
    sh[t] = v;
    __syncthreads();
    for (int d = 1; d < SCAN_B; d <<= 1) {
        int x = (t >= d) ? sh[t - d] : 0;
        __syncthreads();
        sh[t] += x;
        __syncthreads();
    }
    if (g < n) off[g] = sh[t] - v;               // local exclusive
    if (t == SCAN_B - 1) bsum[blockIdx.x] = sh[t];
}

// --- 2b. scan the (<=1024) block sums in one block, in-place exclusive ---
__global__ __launch_bounds__(SCAN_B) void scan2_kernel(int* __restrict__ bsum, int nb) {
    __shared__ int sh[SCAN_B];
    int t = threadIdx.x;
    int v = (t < nb) ? bsum[t] : 0;
    sh[t] = v;
    __syncthreads();
    for (int d = 1; d < SCAN_B; d <<= 1) {
        int x = (t >= d) ? sh[t - d] : 0;
        __syncthreads();
        sh[t] += x;
        __syncthreads();
    }
    if (t < nb) bsum[t] = sh[t] - v;
}

// --- 2c. finalize offsets, init scatter cursors, compute norm_l = rsqrt(max(deg_o,1)) ---
__global__ void finalize_kernel(int* __restrict__ off, const int* __restrict__ bsum,
                                int* __restrict__ cursor, const int* __restrict__ deg_o,
                                float* __restrict__ norm_l, int n) {
    int g = blockIdx.x * blockDim.x + threadIdx.x;
    if (g >= n) return;
    int o = off[g] + bsum[g >> 10];              // SCAN_B == 1024
    off[g] = o;
    cursor[g] = o;
    int d = deg_o[g]; if (d < 1) d = 1;
    norm_l[g] = rsqrtf((float)d);
}

// --- 3. counting-sort scatter: col[] gets src ids grouped by dst ---
__global__ void scatter_kernel(const int* __restrict__ src, const int* __restrict__ dst,
                               int* __restrict__ cursor, int* __restrict__ col, int n_edges) {
    int t = blockIdx.x * blockDim.x + threadIdx.x;
    int e = t * 4;
    if (e + 3 < n_edges) {
        int4 s4 = *(const int4*)(src + e);
        int4 d4 = *(const int4*)(dst + e);
        col[atomicAdd(&cursor[d4.x], 1)] = s4.x;
        col[atomicAdd(&cursor[d4.y], 1)] = s4.y;
        col[atomicAdd(&cursor[d4.z], 1)] = s4.z;
        col[atomicAdd(&cursor[d4.w], 1)] = s4.w;
    } else {
        for (int i = e; i < n_edges; i++)
            col[atomicAdd(&cursor[dst[i]], 1)] = src[i];
    }
}

// --- 4. fp16 pre-scaled features: feat16 = (half)(feat * norm_l[row]) ---
__global__ void convert_kernel(const float* __restrict__ feat, const float* __restrict__ norm_l,
                               __half* __restrict__ feat16, int n_nodes) {
    int t = blockIdx.x * blockDim.x + threadIdx.x;
    int total = n_nodes * (D_FEAT / 8);
    if (t >= total) return;
    float nl = norm_l[t >> 4];                   // 16 threads per 128-elem row
    const float4* fp = (const float4*)feat + (size_t)t * 2;
    float4 a = fp[0], b = fp[1];
    __half2 h0 = __floats2half2_rn(a.x * nl, a.y * nl);
    __half2 h1 = __floats2half2_rn(a.z * nl, a.w * nl);
    __half2 h2 = __floats2half2_rn(b.x * nl, b.y * nl);
    __half2 h3 = __floats2half2_rn(b.z * nl, b.w * nl);
    uint4 o;
    o.x = *(unsigned int*)&h0; o.y = *(unsigned int*)&h1;
    o.z = *(unsigned int*)&h2; o.w = *(unsigned int*)&h3;
    ((uint4*)feat16)[t] = o;
}

// --- 5. CSR pull: one 64-lane wave per dst node; edge list known upfront, so
//     col is read coalesced (1 load / 64 edges) and 8 independent row gathers
//     stay in flight. No pointer chase, no rec[] reads. ---
__global__ __launch_bounds__(256) void pull_csr_kernel(
        const __half* __restrict__ feat16, const int* __restrict__ col,
        const int* __restrict__ off, const int* __restrict__ endp,
        float* __restrict__ out, int n_nodes) {
    int wid  = (int)(((long long)blockIdx.x * blockDim.x + threadIdx.x) >> 6);
    int lane = threadIdx.x & 63;
    if (wid >= n_nodes) return;
    int s = __builtin_amdgcn_readfirstlane(off[wid]);
    int e = __builtin_amdgcn_readfirstlane(endp[wid]);   // cursor after scatter == row end
    float accx = 0.f, accy = 0.f;
    const __half2* lrow = (const __half2*)feat16 + lane; // lane's 4B slot within any row

    for (int base = s; base < e; base += 64) {
        int m = e - base; if (m > 64) m = 64;
        int cv = (lane < m) ? col[base + lane] : 0;      // coalesced index chunk
        int k = 0;
        for (; k + 8 <= m; k += 8) {
            #pragma unroll
            for (int j = 0; j < 8; ++j) {                // 8 gathers in flight
                int idx = __shfl(cv, k + j, 64);
                __half2 h = lrow[(size_t)(unsigned)idx << 6];   // idx*256 B row
                float2 f = __half22float2(h);
                accx += f.x; accy += f.y;
            }
        }
        for (; k < m; ++k) {
            int idx = __shfl(cv, k, 64);
            __half2 h = lrow[(size_t)(unsigned)idx << 6];
            float2 f = __half22float2(h);
            accx += f.x; accy += f.y;
        }
    }

    int cnt = e - s; if (cnt < 1) cnt = 1;
    float nr = rsqrtf((float)cnt);
    f32x2 r; r.x = accx * nr; r.y = accy * nr;
    // non-temporal: out is write-once 51 MB -- don't evict the fp16 table from L2
    __builtin_nontemporal_store(r, (f32x2*)(out + (size_t)wid * D_FEAT) + lane);
}

extern "C" void kernel_launch(void* const* d_in, const int* in_sizes, int n_in,
                              void* d_out, int out_size, void* d_ws, size_t ws_size,
                              hipStream_t stream) {
    const float* feat = (const float*)d_in[0];
    const int*   src  = (const int*)d_in[1];
    const int*   dst  = (const int*)d_in[2];
    float* out = (float*)d_out;

    const int n_nodes = in_sizes[0] / D_FEAT;   // 100000
    const int n_edges = in_sizes[1];            // 1600000

    // ws layout: deg_o[n] deg_i[n] off[n] cursor[n] norm_l[n] bsum[1024] col[E] feat16[n*128]
    // total = 5n*4 + 4K + E*4 + n*256 ~= 34.0 MB (previous session proved >= 39.2 MB usable)
    int*    deg_o  = (int*)d_ws;
    int*    deg_i  = deg_o + n_nodes;
    int*    off    = deg_i + n_nodes;
    int*    cursor = off + n_nodes;
    float*  norm_l = (float*)(cursor + n_nodes);
    int*    bsum   = (int*)(norm_l + n_nodes);
    int*    col    = bsum + SCAN_B;
    __half* feat16 = (__half*)(col + n_edges);

    hipMemsetAsync(deg_o, 0, (size_t)2 * n_nodes * sizeof(int), stream);

    {   // 1. degrees
        int nthreads = (n_edges + 3) / 4;
        degree_kernel<<<(nthreads + 255) / 256, 256, 0, stream>>>(src, dst, deg_o, deg_i, n_edges);
    }
    {   // 2. exclusive scan of in-degree -> off, cursor; norm_l from deg_o
        int nb = (n_nodes + SCAN_B - 1) / SCAN_B;            // 98
        scan1_kernel<<<nb, SCAN_B, 0, stream>>>(deg_i, off, bsum, n_nodes);
        scan2_kernel<<<1, SCAN_B, 0, stream>>>(bsum, nb);
        finalize_kernel<<<(n_nodes + 255) / 256, 256, 0, stream>>>(off, bsum, cursor, deg_o,
                                                                   norm_l, n_nodes);
    }
    {   // 3. fp16 pre-scaled features
        int total = n_nodes * (D_FEAT / 8);
        convert_kernel<<<(total + 255) / 256, 256, 0, stream>>>(feat, norm_l, feat16, n_nodes);
    }
    {   // 4. counting-sort edges into CSR
        int nthreads = (n_edges + 3) / 4;
        scatter_kernel<<<(nthreads + 255) / 256, 256, 0, stream>>>(src, dst, cursor, col, n_edges);
    }
    {   // 5. pull: one wave per node; cursor now holds row ends
        long long total = (long long)n_nodes * 64;
        pull_csr_kernel<<<(int)((total + 255) / 256), 256, 0, stream>>>(feat16, col, off, cursor,
                                                                        out, n_nodes);
    }
}